// Round 1
// baseline (1195.068 us; speedup 1.0000x reference)
//
#include <hip/hip_runtime.h>

#define D 64

// ---------------------------------------------------------------------------
// Kernel 1: agg = x  (handles the (1+eps)*x_i term, eps=0, and un-poisons out)
// ---------------------------------------------------------------------------
__global__ __launch_bounds__(256) void init_copy_kernel(const float4* __restrict__ x,
                                                        float4* __restrict__ agg,
                                                        int n4) {
    int gid = blockIdx.x * 256 + threadIdx.x;
    if (gid < n4) agg[gid] = x[gid];
}

// ---------------------------------------------------------------------------
// Kernel 2: agg[dst] += x[src]   (edge-parallel, HW fp32 atomics)
// One thread per (edge, float4 group): 16 threads per edge.
// ---------------------------------------------------------------------------
__global__ __launch_bounds__(256) void scatter_kernel(const float* __restrict__ x,
                                                      const int* __restrict__ src,
                                                      const int* __restrict__ dst,
                                                      float* __restrict__ agg,
                                                      int nEdges) {
    int gid = blockIdx.x * 256 + threadIdx.x;
    int e = gid >> 4;
    if (e >= nEdges) return;
    int f = (gid & 15) * 4;
    int s = src[e];
    int d = dst[e];
    float4 v = *(const float4*)(x + s * D + f);
    float* p = agg + d * D + f;
#if defined(__gfx90a__) || defined(__gfx940__) || defined(__gfx941__) || defined(__gfx942__) || defined(__gfx950__) || 1
    unsafeAtomicAdd(p + 0, v.x);
    unsafeAtomicAdd(p + 1, v.y);
    unsafeAtomicAdd(p + 2, v.z);
    unsafeAtomicAdd(p + 3, v.w);
#else
    atomicAdd(p + 0, v.x);
    atomicAdd(p + 1, v.y);
    atomicAdd(p + 2, v.z);
    atomicAdd(p + 3, v.w);
#endif
}

// ---------------------------------------------------------------------------
// Kernel 3: out[n] = relu(h[n] @ W1 + b1) @ W2 + b2, h = agg (in-place safe:
// each thread reads only its own 64 floats fully before writing them back).
// Thread-per-node; weights in LDS, read as wave-uniform float4 broadcasts;
// h/acc fully unrolled into VGPRs.
// ---------------------------------------------------------------------------
__global__ __launch_bounds__(256) void mlp_kernel(const float* hin,
                                                  const float* __restrict__ W1,
                                                  const float* __restrict__ b1,
                                                  const float* __restrict__ W2,
                                                  const float* __restrict__ b2,
                                                  float* out,
                                                  int nNodes) {
    __shared__ float sW1[D * D];
    __shared__ float sW2[D * D];
    __shared__ float sb1[D];
    __shared__ float sb2[D];

    int tid = threadIdx.x;
    // Cooperative load of weights: 4096 floats each = 1024 float4; 256 thr x 4.
    const float4* w1v = (const float4*)W1;
    const float4* w2v = (const float4*)W2;
    float4* s1v = (float4*)sW1;
    float4* s2v = (float4*)sW2;
#pragma unroll
    for (int i = 0; i < 4; i++) {
        int idx = tid + 256 * i;
        s1v[idx] = w1v[idx];
        s2v[idx] = w2v[idx];
    }
    if (tid < D) {
        sb1[tid] = b1[tid];
        sb2[tid] = b2[tid];
    }
    __syncthreads();

    int node = blockIdx.x * 256 + tid;
    if (node >= nNodes) return;

    const float4* hp = (const float4*)(hin + node * D);
    float h[D];
#pragma unroll
    for (int i = 0; i < 16; i++) {
        float4 v = hp[i];
        h[4 * i + 0] = v.x;
        h[4 * i + 1] = v.y;
        h[4 * i + 2] = v.z;
        h[4 * i + 3] = v.w;
    }

    float acc[D];
    // ---- layer 1 ----
#pragma unroll
    for (int j = 0; j < D; j++) acc[j] = sb1[j];
#pragma unroll
    for (int k = 0; k < D; k++) {
        float hk = h[k];
        const float4* wr = (const float4*)(sW1 + k * D);
#pragma unroll
        for (int j = 0; j < 16; j++) {
            float4 w = wr[j];  // wave-uniform LDS broadcast
            acc[4 * j + 0] = fmaf(hk, w.x, acc[4 * j + 0]);
            acc[4 * j + 1] = fmaf(hk, w.y, acc[4 * j + 1]);
            acc[4 * j + 2] = fmaf(hk, w.z, acc[4 * j + 2]);
            acc[4 * j + 3] = fmaf(hk, w.w, acc[4 * j + 3]);
        }
    }
    // ReLU
#pragma unroll
    for (int j = 0; j < D; j++) h[j] = fmaxf(acc[j], 0.0f);

    // ---- layer 2 ----
#pragma unroll
    for (int j = 0; j < D; j++) acc[j] = sb2[j];
#pragma unroll
    for (int k = 0; k < D; k++) {
        float hk = h[k];
        const float4* wr = (const float4*)(sW2 + k * D);
#pragma unroll
        for (int j = 0; j < 16; j++) {
            float4 w = wr[j];
            acc[4 * j + 0] = fmaf(hk, w.x, acc[4 * j + 0]);
            acc[4 * j + 1] = fmaf(hk, w.y, acc[4 * j + 1]);
            acc[4 * j + 2] = fmaf(hk, w.z, acc[4 * j + 2]);
            acc[4 * j + 3] = fmaf(hk, w.w, acc[4 * j + 3]);
        }
    }

    float4* op = (float4*)(out + node * D);
#pragma unroll
    for (int i = 0; i < 16; i++) {
        float4 v;
        v.x = acc[4 * i + 0];
        v.y = acc[4 * i + 1];
        v.z = acc[4 * i + 2];
        v.w = acc[4 * i + 3];
        op[i] = v;
    }
}

extern "C" void kernel_launch(void* const* d_in, const int* in_sizes, int n_in,
                              void* d_out, int out_size, void* d_ws, size_t ws_size,
                              hipStream_t stream) {
    const float* x  = (const float*)d_in[0];
    const int*   ei = (const int*)d_in[1];   // [2, E] row-major, int32
    const float* W1 = (const float*)d_in[2];
    const float* b1 = (const float*)d_in[3];
    const float* W2 = (const float*)d_in[4];
    const float* b2 = (const float*)d_in[5];
    float* out = (float*)d_out;

    const int nNodes = in_sizes[0] / D;
    const int nEdges = in_sizes[1] / 2;
    const int* src = ei;
    const int* dst = ei + nEdges;

    // 1) agg = x  (into d_out)
    {
        int n4 = nNodes * (D / 4);
        int blocks = (n4 + 255) / 256;
        init_copy_kernel<<<blocks, 256, 0, stream>>>((const float4*)x, (float4*)out, n4);
    }
    // 2) agg[dst] += x[src]
    {
        long long work = (long long)nEdges * 16;
        int blocks = (int)((work + 255) / 256);
        scatter_kernel<<<blocks, 256, 0, stream>>>(x, src, dst, out, nEdges);
    }
    // 3) out = MLP(agg) in-place
    {
        int blocks = (nNodes + 255) / 256;
        mlp_kernel<<<blocks, 256, 0, stream>>>(out, W1, b1, W2, b2, out, nNodes);
    }
}

// Round 2
// 420.943 us; speedup vs baseline: 2.8390x; 2.8390x over previous
//
#include <hip/hip_runtime.h>

#define D 64

// ---------------------------------------------------------------------------
// CSR-by-destination build: zero -> histogram -> exclusive scan -> fill.
// d_ws layout: off[int, N+1] | cur[int, N] | ssrc[int, E]   (~5.8 MB)
// ---------------------------------------------------------------------------

__global__ __launch_bounds__(256) void zero_kernel(int* __restrict__ p, int n) {
    int gid = blockIdx.x * 256 + threadIdx.x;
    if (gid < n) p[gid] = 0;
}

__global__ __launch_bounds__(256) void hist_kernel(const int* __restrict__ dst,
                                                   int* __restrict__ counts,
                                                   int nEdges) {
    int gid = blockIdx.x * 256 + threadIdx.x;
    if (gid < nEdges) atomicAdd(&counts[dst[gid]], 1);
}

// Single-block chunked exclusive scan over counts[0..N) (in-place into off),
// also copies the result into cur. off[N] = nEdges.
__global__ __launch_bounds__(1024) void scan_kernel(int* __restrict__ off,
                                                    int* __restrict__ cur,
                                                    int nNodes, int nEdges) {
    __shared__ int waveSums[16];
    __shared__ int sBase;
    int tid = threadIdx.x;
    int lane = tid & 63;
    int wave = tid >> 6;
    if (tid == 0) sBase = 0;
    __syncthreads();

    for (int base = 0; base < nNodes; base += 1024) {
        int i = base + tid;
        int v = (i < nNodes) ? off[i] : 0;
        // inclusive scan within wave (64 lanes)
        int incl = v;
#pragma unroll
        for (int d = 1; d < 64; d <<= 1) {
            int t = __shfl_up(incl, d, 64);
            if (lane >= d) incl += t;
        }
        if (lane == 63) waveSums[wave] = incl;
        __syncthreads();                       // (1) waveSums written
        if (wave == 0) {
            int wv = (lane < 16) ? waveSums[lane] : 0;
            int s = wv;
#pragma unroll
            for (int d = 1; d < 16; d <<= 1) {
                int t = __shfl_up(s, d, 64);
                if (lane >= d) s += t;
            }
            if (lane < 16) waveSums[lane] = s - wv;  // exclusive wave offsets
        }
        __syncthreads();                       // (2) wave offsets ready
        int chunkBase = sBase;
        int excl = chunkBase + waveSums[wave] + incl - v;
        if (i < nNodes) { off[i] = excl; cur[i] = excl; }
        __syncthreads();                       // (3) everyone has read sBase/waveSums
        if (tid == 1023) sBase = chunkBase + waveSums[15] + incl;  // chunk total
        __syncthreads();                       // (4) sBase update visible
    }
    if (tid == 0) off[nNodes] = nEdges;
}

__global__ __launch_bounds__(256) void fill_kernel(const int* __restrict__ src,
                                                   const int* __restrict__ dst,
                                                   int* __restrict__ cur,
                                                   int* __restrict__ ssrc,
                                                   int nEdges) {
    int gid = blockIdx.x * 256 + threadIdx.x;
    if (gid >= nEdges) return;
    int d = dst[gid];
    int p = atomicAdd(&cur[d], 1);
    ssrc[p] = src[gid];
}

// ---------------------------------------------------------------------------
// Aggregate: out[n] = x[n] + sum_{e in CSR[n]} x[ssrc[e]]
// 16 threads per node; each owns a float4 column group; register accumulate.
// ---------------------------------------------------------------------------
__global__ __launch_bounds__(256) void aggregate_kernel(const float* __restrict__ x,
                                                        const int* __restrict__ off,
                                                        const int* __restrict__ ssrc,
                                                        float* __restrict__ out,
                                                        int nNodes) {
    int gid = blockIdx.x * 256 + threadIdx.x;
    int n = gid >> 4;
    if (n >= nNodes) return;
    int f = (gid & 15) * 4;
    float4 acc = *(const float4*)(x + (size_t)n * D + f);
    int e0 = off[n], e1 = off[n + 1];
    for (int e = e0; e < e1; e++) {
        int s = ssrc[e];
        float4 v = *(const float4*)(x + (size_t)s * D + f);
        acc.x += v.x; acc.y += v.y; acc.z += v.z; acc.w += v.w;
    }
    *(float4*)(out + (size_t)n * D + f) = acc;
}

// ---------------------------------------------------------------------------
// MLP: out[n] = relu(h[n] @ W1 + b1) @ W2 + b2 (in-place on out)
// ---------------------------------------------------------------------------
__global__ __launch_bounds__(256) void mlp_kernel(const float* hin,
                                                  const float* __restrict__ W1,
                                                  const float* __restrict__ b1,
                                                  const float* __restrict__ W2,
                                                  const float* __restrict__ b2,
                                                  float* out,
                                                  int nNodes) {
    __shared__ float sW1[D * D];
    __shared__ float sW2[D * D];
    __shared__ float sb1[D];
    __shared__ float sb2[D];

    int tid = threadIdx.x;
    const float4* w1v = (const float4*)W1;
    const float4* w2v = (const float4*)W2;
    float4* s1v = (float4*)sW1;
    float4* s2v = (float4*)sW2;
#pragma unroll
    for (int i = 0; i < 4; i++) {
        int idx = tid + 256 * i;
        s1v[idx] = w1v[idx];
        s2v[idx] = w2v[idx];
    }
    if (tid < D) {
        sb1[tid] = b1[tid];
        sb2[tid] = b2[tid];
    }
    __syncthreads();

    int node = blockIdx.x * 256 + tid;
    if (node >= nNodes) return;

    const float4* hp = (const float4*)(hin + (size_t)node * D);
    float h[D];
#pragma unroll
    for (int i = 0; i < 16; i++) {
        float4 v = hp[i];
        h[4 * i + 0] = v.x;
        h[4 * i + 1] = v.y;
        h[4 * i + 2] = v.z;
        h[4 * i + 3] = v.w;
    }

    float acc[D];
#pragma unroll
    for (int j = 0; j < D; j++) acc[j] = sb1[j];
#pragma unroll
    for (int k = 0; k < D; k++) {
        float hk = h[k];
        const float4* wr = (const float4*)(sW1 + k * D);
#pragma unroll
        for (int j = 0; j < 16; j++) {
            float4 w = wr[j];
            acc[4 * j + 0] = fmaf(hk, w.x, acc[4 * j + 0]);
            acc[4 * j + 1] = fmaf(hk, w.y, acc[4 * j + 1]);
            acc[4 * j + 2] = fmaf(hk, w.z, acc[4 * j + 2]);
            acc[4 * j + 3] = fmaf(hk, w.w, acc[4 * j + 3]);
        }
    }
#pragma unroll
    for (int j = 0; j < D; j++) h[j] = fmaxf(acc[j], 0.0f);

#pragma unroll
    for (int j = 0; j < D; j++) acc[j] = sb2[j];
#pragma unroll
    for (int k = 0; k < D; k++) {
        float hk = h[k];
        const float4* wr = (const float4*)(sW2 + k * D);
#pragma unroll
        for (int j = 0; j < 16; j++) {
            float4 w = wr[j];
            acc[4 * j + 0] = fmaf(hk, w.x, acc[4 * j + 0]);
            acc[4 * j + 1] = fmaf(hk, w.y, acc[4 * j + 1]);
            acc[4 * j + 2] = fmaf(hk, w.z, acc[4 * j + 2]);
            acc[4 * j + 3] = fmaf(hk, w.w, acc[4 * j + 3]);
        }
    }

    float4* op = (float4*)(out + (size_t)node * D);
#pragma unroll
    for (int i = 0; i < 16; i++) {
        float4 v;
        v.x = acc[4 * i + 0];
        v.y = acc[4 * i + 1];
        v.z = acc[4 * i + 2];
        v.w = acc[4 * i + 3];
        op[i] = v;
    }
}

extern "C" void kernel_launch(void* const* d_in, const int* in_sizes, int n_in,
                              void* d_out, int out_size, void* d_ws, size_t ws_size,
                              hipStream_t stream) {
    const float* x  = (const float*)d_in[0];
    const int*   ei = (const int*)d_in[1];   // [2, E] row-major, int32
    const float* W1 = (const float*)d_in[2];
    const float* b1 = (const float*)d_in[3];
    const float* W2 = (const float*)d_in[4];
    const float* b2 = (const float*)d_in[5];
    float* out = (float*)d_out;

    const int nNodes = in_sizes[0] / D;
    const int nEdges = in_sizes[1] / 2;
    const int* src = ei;
    const int* dst = ei + nEdges;

    int* off  = (int*)d_ws;            // N+1
    int* cur  = off + (nNodes + 1);    // N
    int* ssrc = cur + nNodes;          // E

    // 1) counts = 0
    zero_kernel<<<(nNodes + 1 + 255) / 256, 256, 0, stream>>>(off, nNodes + 1);
    // 2) histogram of dst
    hist_kernel<<<(nEdges + 255) / 256, 256, 0, stream>>>(dst, off, nEdges);
    // 3) exclusive scan -> off, cur
    scan_kernel<<<1, 1024, 0, stream>>>(off, cur, nNodes, nEdges);
    // 4) fill sorted src lists
    fill_kernel<<<(nEdges + 255) / 256, 256, 0, stream>>>(src, dst, cur, ssrc, nEdges);
    // 5) aggregate: out = x + segment_sum(x[src])
    {
        long long work = (long long)nNodes * 16;
        aggregate_kernel<<<(int)((work + 255) / 256), 256, 0, stream>>>(x, off, ssrc, out, nNodes);
    }
    // 6) MLP in-place
    mlp_kernel<<<(nNodes + 255) / 256, 256, 0, stream>>>(out, W1, b1, W2, b2, out, nNodes);
}

// Round 3
// 324.967 us; speedup vs baseline: 3.6775x; 1.2953x over previous
//
#include <hip/hip_runtime.h>

#define D 64
#define SCAN_CHUNK 1024

// ---------------------------------------------------------------------------
// d_ws layout: off[int, N+1] | cur[int, N] | ssrc[int, E] | blockSums[int, nSB]
// ---------------------------------------------------------------------------

__global__ __launch_bounds__(256) void zero_kernel(int* __restrict__ p, int n) {
    int gid = blockIdx.x * 256 + threadIdx.x;
    if (gid < n) p[gid] = 0;
}

__global__ __launch_bounds__(256) void hist_kernel(const int* __restrict__ dst,
                                                   int* __restrict__ counts,
                                                   int nEdges) {
    int gid = blockIdx.x * 256 + threadIdx.x;
    if (gid < nEdges) atomicAdd(&counts[dst[gid]], 1);
}

// ---- scan pass A: blockSums[b] = sum(counts[b*1024 .. b*1024+1024)) ----
__global__ __launch_bounds__(256) void scan_reduce_kernel(const int* __restrict__ counts,
                                                          int* __restrict__ blockSums,
                                                          int nNodes) {
    __shared__ int ws[4];
    int base = blockIdx.x * SCAN_CHUNK;
    int tid = threadIdx.x;
    int s = 0;
#pragma unroll
    for (int i = 0; i < 4; i++) {
        int idx = base + tid + 256 * i;
        if (idx < nNodes) s += counts[idx];
    }
#pragma unroll
    for (int d = 32; d > 0; d >>= 1) s += __shfl_xor(s, d, 64);
    if ((tid & 63) == 0) ws[tid >> 6] = s;
    __syncthreads();
    if (tid == 0) blockSums[blockIdx.x] = ws[0] + ws[1] + ws[2] + ws[3];
}

// ---- scan pass B: exclusive scan of blockSums (nSB <= 256), 1 block ----
__global__ __launch_bounds__(256) void scan_sums_kernel(int* __restrict__ blockSums,
                                                        int* __restrict__ off,
                                                        int nSB, int nNodes, int nEdges) {
    __shared__ int ws[4];
    int tid = threadIdx.x;
    int lane = tid & 63;
    int wave = tid >> 6;
    int v = (tid < nSB) ? blockSums[tid] : 0;
    int incl = v;
#pragma unroll
    for (int d = 1; d < 64; d <<= 1) {
        int t = __shfl_up(incl, d, 64);
        if (lane >= d) incl += t;
    }
    if (lane == 63) ws[wave] = incl;
    __syncthreads();
    int waveOff = 0;
#pragma unroll
    for (int w = 0; w < 4; w++)
        if (w < wave) waveOff += ws[w];
    if (tid < nSB) blockSums[tid] = waveOff + incl - v;  // exclusive
    if (tid == 0) off[nNodes] = nEdges;
}

// ---- scan pass C: rescan each chunk, add base, write off & cur ----
__global__ __launch_bounds__(1024) void scan_write_kernel(int* __restrict__ off,
                                                          int* __restrict__ cur,
                                                          const int* __restrict__ blockSums,
                                                          int nNodes) {
    __shared__ int waveSums[16];
    int tid = threadIdx.x;
    int lane = tid & 63;
    int wave = tid >> 6;
    int i = blockIdx.x * SCAN_CHUNK + tid;
    int v = (i < nNodes) ? off[i] : 0;
    int incl = v;
#pragma unroll
    for (int d = 1; d < 64; d <<= 1) {
        int t = __shfl_up(incl, d, 64);
        if (lane >= d) incl += t;
    }
    if (lane == 63) waveSums[wave] = incl;
    __syncthreads();
    if (wave == 0) {
        int wv = (lane < 16) ? waveSums[lane] : 0;
        int s = wv;
#pragma unroll
        for (int d = 1; d < 16; d <<= 1) {
            int t = __shfl_up(s, d, 64);
            if (lane >= d) s += t;
        }
        if (lane < 16) waveSums[lane] = s - wv;  // exclusive wave offsets
    }
    __syncthreads();
    if (i < nNodes) {
        int excl = blockSums[blockIdx.x] + waveSums[wave] + incl - v;
        off[i] = excl;
        cur[i] = excl;
    }
}

__global__ __launch_bounds__(256) void fill_kernel(const int* __restrict__ src,
                                                   const int* __restrict__ dst,
                                                   int* __restrict__ cur,
                                                   int* __restrict__ ssrc,
                                                   int nEdges) {
    int gid = blockIdx.x * 256 + threadIdx.x;
    if (gid >= nEdges) return;
    int d = dst[gid];
    int p = atomicAdd(&cur[d], 1);
    ssrc[p] = src[gid];
}

// ---------------------------------------------------------------------------
// Aggregate: out[n] = x[n] + sum_{e in CSR[n]} x[ssrc[e]]
// ---------------------------------------------------------------------------
__global__ __launch_bounds__(256) void aggregate_kernel(const float* __restrict__ x,
                                                        const int* __restrict__ off,
                                                        const int* __restrict__ ssrc,
                                                        float* __restrict__ out,
                                                        int nNodes) {
    int gid = blockIdx.x * 256 + threadIdx.x;
    int n = gid >> 4;
    if (n >= nNodes) return;
    int f = (gid & 15) * 4;
    float4 acc = *(const float4*)(x + (size_t)n * D + f);
    int e0 = off[n], e1 = off[n + 1];
    for (int e = e0; e < e1; e++) {
        int s = ssrc[e];
        float4 v = *(const float4*)(x + (size_t)s * D + f);
        acc.x += v.x; acc.y += v.y; acc.z += v.z; acc.w += v.w;
    }
    *(float4*)(out + (size_t)n * D + f) = acc;
}

// ---------------------------------------------------------------------------
// MLP: out[n] = relu(h[n] @ W1 + b1) @ W2 + b2 (in-place on out)
// ---------------------------------------------------------------------------
__global__ __launch_bounds__(256) void mlp_kernel(const float* hin,
                                                  const float* __restrict__ W1,
                                                  const float* __restrict__ b1,
                                                  const float* __restrict__ W2,
                                                  const float* __restrict__ b2,
                                                  float* out,
                                                  int nNodes) {
    __shared__ float sW1[D * D];
    __shared__ float sW2[D * D];
    __shared__ float sb1[D];
    __shared__ float sb2[D];

    int tid = threadIdx.x;
    const float4* w1v = (const float4*)W1;
    const float4* w2v = (const float4*)W2;
    float4* s1v = (float4*)sW1;
    float4* s2v = (float4*)sW2;
#pragma unroll
    for (int i = 0; i < 4; i++) {
        int idx = tid + 256 * i;
        s1v[idx] = w1v[idx];
        s2v[idx] = w2v[idx];
    }
    if (tid < D) {
        sb1[tid] = b1[tid];
        sb2[tid] = b2[tid];
    }
    __syncthreads();

    int node = blockIdx.x * 256 + tid;
    if (node >= nNodes) return;

    const float4* hp = (const float4*)(hin + (size_t)node * D);
    float h[D];
#pragma unroll
    for (int i = 0; i < 16; i++) {
        float4 v = hp[i];
        h[4 * i + 0] = v.x;
        h[4 * i + 1] = v.y;
        h[4 * i + 2] = v.z;
        h[4 * i + 3] = v.w;
    }

    float acc[D];
#pragma unroll
    for (int j = 0; j < D; j++) acc[j] = sb1[j];
#pragma unroll
    for (int k = 0; k < D; k++) {
        float hk = h[k];
        const float4* wr = (const float4*)(sW1 + k * D);
#pragma unroll
        for (int j = 0; j < 16; j++) {
            float4 w = wr[j];
            acc[4 * j + 0] = fmaf(hk, w.x, acc[4 * j + 0]);
            acc[4 * j + 1] = fmaf(hk, w.y, acc[4 * j + 1]);
            acc[4 * j + 2] = fmaf(hk, w.z, acc[4 * j + 2]);
            acc[4 * j + 3] = fmaf(hk, w.w, acc[4 * j + 3]);
        }
    }
#pragma unroll
    for (int j = 0; j < D; j++) h[j] = fmaxf(acc[j], 0.0f);

#pragma unroll
    for (int j = 0; j < D; j++) acc[j] = sb2[j];
#pragma unroll
    for (int k = 0; k < D; k++) {
        float hk = h[k];
        const float4* wr = (const float4*)(sW2 + k * D);
#pragma unroll
        for (int j = 0; j < 16; j++) {
            float4 w = wr[j];
            acc[4 * j + 0] = fmaf(hk, w.x, acc[4 * j + 0]);
            acc[4 * j + 1] = fmaf(hk, w.y, acc[4 * j + 1]);
            acc[4 * j + 2] = fmaf(hk, w.z, acc[4 * j + 2]);
            acc[4 * j + 3] = fmaf(hk, w.w, acc[4 * j + 3]);
        }
    }

    float4* op = (float4*)(out + (size_t)node * D);
#pragma unroll
    for (int i = 0; i < 16; i++) {
        float4 v;
        v.x = acc[4 * i + 0];
        v.y = acc[4 * i + 1];
        v.z = acc[4 * i + 2];
        v.w = acc[4 * i + 3];
        op[i] = v;
    }
}

extern "C" void kernel_launch(void* const* d_in, const int* in_sizes, int n_in,
                              void* d_out, int out_size, void* d_ws, size_t ws_size,
                              hipStream_t stream) {
    const float* x  = (const float*)d_in[0];
    const int*   ei = (const int*)d_in[1];   // [2, E] row-major, int32
    const float* W1 = (const float*)d_in[2];
    const float* b1 = (const float*)d_in[3];
    const float* W2 = (const float*)d_in[4];
    const float* b2 = (const float*)d_in[5];
    float* out = (float*)d_out;

    const int nNodes = in_sizes[0] / D;
    const int nEdges = in_sizes[1] / 2;
    const int* src = ei;
    const int* dst = ei + nEdges;

    const int nSB = (nNodes + SCAN_CHUNK - 1) / SCAN_CHUNK;  // <= 256 for N <= 256K

    int* off  = (int*)d_ws;            // N+1
    int* cur  = off + (nNodes + 1);    // N
    int* ssrc = cur + nNodes;          // E
    int* blockSums = ssrc + nEdges;    // nSB

    // 1) counts = 0
    zero_kernel<<<(nNodes + 1 + 255) / 256, 256, 0, stream>>>(off, nNodes + 1);
    // 2) histogram of dst
    hist_kernel<<<(nEdges + 255) / 256, 256, 0, stream>>>(dst, off, nEdges);
    // 3) multi-block exclusive scan -> off, cur
    scan_reduce_kernel<<<nSB, 256, 0, stream>>>(off, blockSums, nNodes);
    scan_sums_kernel<<<1, 256, 0, stream>>>(blockSums, off, nSB, nNodes, nEdges);
    scan_write_kernel<<<nSB, 1024, 0, stream>>>(off, cur, blockSums, nNodes);
    // 4) fill sorted src lists
    fill_kernel<<<(nEdges + 255) / 256, 256, 0, stream>>>(src, dst, cur, ssrc, nEdges);
    // 5) aggregate: out = x + segment_sum(x[src])
    {
        long long work = (long long)nNodes * 16;
        aggregate_kernel<<<(int)((work + 255) / 256), 256, 0, stream>>>(x, off, ssrc, out, nNodes);
    }
    // 6) MLP in-place
    mlp_kernel<<<(nNodes + 255) / 256, 256, 0, stream>>>(out, W1, b1, W2, b2, out, nNodes);
}

// Round 4
// 299.204 us; speedup vs baseline: 3.9942x; 1.0861x over previous
//
#include <hip/hip_runtime.h>

#define D 64
#define SCAN_CHUNK 1024
#define NXCD 8

// ---------------------------------------------------------------------------
// d_ws layout: off[int, N+1] | cur[int, N] | ssrc[int, E] | blockSums[int, nSB]
// ---------------------------------------------------------------------------

__global__ __launch_bounds__(256) void zero_kernel(int* __restrict__ p, int n) {
    int gid = blockIdx.x * 256 + threadIdx.x;
    if (gid < n) p[gid] = 0;
}

__global__ __launch_bounds__(256) void hist_kernel(const int* __restrict__ dst,
                                                   int* __restrict__ counts,
                                                   int nEdges) {
    int gid = blockIdx.x * 256 + threadIdx.x;
    if (gid < nEdges) atomicAdd(&counts[dst[gid]], 1);
}

// ---- scan pass A: blockSums[b] = sum(counts[b*1024 .. b*1024+1024)) ----
__global__ __launch_bounds__(256) void scan_reduce_kernel(const int* __restrict__ counts,
                                                          int* __restrict__ blockSums,
                                                          int nNodes) {
    __shared__ int ws[4];
    int base = blockIdx.x * SCAN_CHUNK;
    int tid = threadIdx.x;
    int s = 0;
#pragma unroll
    for (int i = 0; i < 4; i++) {
        int idx = base + tid + 256 * i;
        if (idx < nNodes) s += counts[idx];
    }
#pragma unroll
    for (int d = 32; d > 0; d >>= 1) s += __shfl_xor(s, d, 64);
    if ((tid & 63) == 0) ws[tid >> 6] = s;
    __syncthreads();
    if (tid == 0) blockSums[blockIdx.x] = ws[0] + ws[1] + ws[2] + ws[3];
}

// ---- scan pass B: exclusive scan of blockSums (nSB <= 256), 1 block ----
__global__ __launch_bounds__(256) void scan_sums_kernel(int* __restrict__ blockSums,
                                                        int* __restrict__ off,
                                                        int nSB, int nNodes, int nEdges) {
    __shared__ int ws[4];
    int tid = threadIdx.x;
    int lane = tid & 63;
    int wave = tid >> 6;
    int v = (tid < nSB) ? blockSums[tid] : 0;
    int incl = v;
#pragma unroll
    for (int d = 1; d < 64; d <<= 1) {
        int t = __shfl_up(incl, d, 64);
        if (lane >= d) incl += t;
    }
    if (lane == 63) ws[wave] = incl;
    __syncthreads();
    int waveOff = 0;
#pragma unroll
    for (int w = 0; w < 4; w++)
        if (w < wave) waveOff += ws[w];
    if (tid < nSB) blockSums[tid] = waveOff + incl - v;  // exclusive
    if (tid == 0) off[nNodes] = nEdges;
}

// ---- scan pass C: rescan each chunk, add base, write off & cur ----
__global__ __launch_bounds__(1024) void scan_write_kernel(int* __restrict__ off,
                                                          int* __restrict__ cur,
                                                          const int* __restrict__ blockSums,
                                                          int nNodes) {
    __shared__ int waveSums[16];
    int tid = threadIdx.x;
    int lane = tid & 63;
    int wave = tid >> 6;
    int i = blockIdx.x * SCAN_CHUNK + tid;
    int v = (i < nNodes) ? off[i] : 0;
    int incl = v;
#pragma unroll
    for (int d = 1; d < 64; d <<= 1) {
        int t = __shfl_up(incl, d, 64);
        if (lane >= d) incl += t;
    }
    if (lane == 63) waveSums[wave] = incl;
    __syncthreads();
    if (wave == 0) {
        int wv = (lane < 16) ? waveSums[lane] : 0;
        int s = wv;
#pragma unroll
        for (int d = 1; d < 16; d <<= 1) {
            int t = __shfl_up(s, d, 64);
            if (lane >= d) s += t;
        }
        if (lane < 16) waveSums[lane] = s - wv;  // exclusive wave offsets
    }
    __syncthreads();
    if (i < nNodes) {
        int excl = blockSums[blockIdx.x] + waveSums[wave] + incl - v;
        off[i] = excl;
        cur[i] = excl;
    }
}

// ---------------------------------------------------------------------------
// XCD-partitioned fill: block b handles node range of XCD (b % 8) only, so
// every ssrc cache line is written from a single XCD -> writes coalesce in
// that XCD's L2 instead of bouncing (correctness does NOT depend on the
// blockIdx->XCD mapping; it is a locality heuristic only).
// ---------------------------------------------------------------------------
__global__ __launch_bounds__(256) void fill_xcd_kernel(const int* __restrict__ src,
                                                       const int* __restrict__ dst,
                                                       int* __restrict__ cur,
                                                       int* __restrict__ ssrc,
                                                       int nEdges, int nNodes,
                                                       int blocksPerXcd) {
    int xcd = blockIdx.x % NXCD;
    int slice = blockIdx.x / NXCD;
    int lo = (int)((long long)nNodes * xcd / NXCD);
    int hi = (int)((long long)nNodes * (xcd + 1) / NXCD);
    int per = (nEdges + blocksPerXcd - 1) / blocksPerXcd;
    int e0 = slice * per;
    int e1 = min(e0 + per, nEdges);
    for (int e = e0 + (int)threadIdx.x; e < e1; e += 256) {
        int d = dst[e];
        if (d >= lo && d < hi) {
            int p = atomicAdd(&cur[d], 1);
            ssrc[p] = src[e];
        }
    }
}

// ---------------------------------------------------------------------------
// Aggregate: out[n] = x[n] + sum_{e in CSR[n]} x[ssrc[e]]
// ---------------------------------------------------------------------------
__global__ __launch_bounds__(256) void aggregate_kernel(const float* __restrict__ x,
                                                        const int* __restrict__ off,
                                                        const int* __restrict__ ssrc,
                                                        float* __restrict__ out,
                                                        int nNodes) {
    int gid = blockIdx.x * 256 + threadIdx.x;
    int n = gid >> 4;
    if (n >= nNodes) return;
    int f = (gid & 15) * 4;
    float4 acc = *(const float4*)(x + (size_t)n * D + f);
    int e0 = off[n], e1 = off[n + 1];
    for (int e = e0; e < e1; e++) {
        int s = ssrc[e];
        float4 v = *(const float4*)(x + (size_t)s * D + f);
        acc.x += v.x; acc.y += v.y; acc.z += v.z; acc.w += v.w;
    }
    *(float4*)(out + (size_t)n * D + f) = acc;
}

// ---------------------------------------------------------------------------
// MLP: out[n] = relu(h[n] @ W1 + b1) @ W2 + b2 (in-place on out)
// ---------------------------------------------------------------------------
__global__ __launch_bounds__(256) void mlp_kernel(const float* hin,
                                                  const float* __restrict__ W1,
                                                  const float* __restrict__ b1,
                                                  const float* __restrict__ W2,
                                                  const float* __restrict__ b2,
                                                  float* out,
                                                  int nNodes) {
    __shared__ float sW1[D * D];
    __shared__ float sW2[D * D];
    __shared__ float sb1[D];
    __shared__ float sb2[D];

    int tid = threadIdx.x;
    const float4* w1v = (const float4*)W1;
    const float4* w2v = (const float4*)W2;
    float4* s1v = (float4*)sW1;
    float4* s2v = (float4*)sW2;
#pragma unroll
    for (int i = 0; i < 4; i++) {
        int idx = tid + 256 * i;
        s1v[idx] = w1v[idx];
        s2v[idx] = w2v[idx];
    }
    if (tid < D) {
        sb1[tid] = b1[tid];
        sb2[tid] = b2[tid];
    }
    __syncthreads();

    int node = blockIdx.x * 256 + tid;
    if (node >= nNodes) return;

    const float4* hp = (const float4*)(hin + (size_t)node * D);
    float h[D];
#pragma unroll
    for (int i = 0; i < 16; i++) {
        float4 v = hp[i];
        h[4 * i + 0] = v.x;
        h[4 * i + 1] = v.y;
        h[4 * i + 2] = v.z;
        h[4 * i + 3] = v.w;
    }

    float acc[D];
#pragma unroll
    for (int j = 0; j < D; j++) acc[j] = sb1[j];
#pragma unroll
    for (int k = 0; k < D; k++) {
        float hk = h[k];
        const float4* wr = (const float4*)(sW1 + k * D);
#pragma unroll
        for (int j = 0; j < 16; j++) {
            float4 w = wr[j];
            acc[4 * j + 0] = fmaf(hk, w.x, acc[4 * j + 0]);
            acc[4 * j + 1] = fmaf(hk, w.y, acc[4 * j + 1]);
            acc[4 * j + 2] = fmaf(hk, w.z, acc[4 * j + 2]);
            acc[4 * j + 3] = fmaf(hk, w.w, acc[4 * j + 3]);
        }
    }
#pragma unroll
    for (int j = 0; j < D; j++) h[j] = fmaxf(acc[j], 0.0f);

#pragma unroll
    for (int j = 0; j < D; j++) acc[j] = sb2[j];
#pragma unroll
    for (int k = 0; k < D; k++) {
        float hk = h[k];
        const float4* wr = (const float4*)(sW2 + k * D);
#pragma unroll
        for (int j = 0; j < 16; j++) {
            float4 w = wr[j];
            acc[4 * j + 0] = fmaf(hk, w.x, acc[4 * j + 0]);
            acc[4 * j + 1] = fmaf(hk, w.y, acc[4 * j + 1]);
            acc[4 * j + 2] = fmaf(hk, w.z, acc[4 * j + 2]);
            acc[4 * j + 3] = fmaf(hk, w.w, acc[4 * j + 3]);
        }
    }

    float4* op = (float4*)(out + (size_t)node * D);
#pragma unroll
    for (int i = 0; i < 16; i++) {
        float4 v;
        v.x = acc[4 * i + 0];
        v.y = acc[4 * i + 1];
        v.z = acc[4 * i + 2];
        v.w = acc[4 * i + 3];
        op[i] = v;
    }
}

extern "C" void kernel_launch(void* const* d_in, const int* in_sizes, int n_in,
                              void* d_out, int out_size, void* d_ws, size_t ws_size,
                              hipStream_t stream) {
    const float* x  = (const float*)d_in[0];
    const int*   ei = (const int*)d_in[1];   // [2, E] row-major, int32
    const float* W1 = (const float*)d_in[2];
    const float* b1 = (const float*)d_in[3];
    const float* W2 = (const float*)d_in[4];
    const float* b2 = (const float*)d_in[5];
    float* out = (float*)d_out;

    const int nNodes = in_sizes[0] / D;
    const int nEdges = in_sizes[1] / 2;
    const int* src = ei;
    const int* dst = ei + nEdges;

    const int nSB = (nNodes + SCAN_CHUNK - 1) / SCAN_CHUNK;  // <= 256 for N <= 256K

    int* off  = (int*)d_ws;            // N+1
    int* cur  = off + (nNodes + 1);    // N
    int* ssrc = cur + nNodes;          // E
    int* blockSums = ssrc + nEdges;    // nSB

    // 1) counts = 0
    zero_kernel<<<(nNodes + 1 + 255) / 256, 256, 0, stream>>>(off, nNodes + 1);
    // 2) histogram of dst
    hist_kernel<<<(nEdges + 255) / 256, 256, 0, stream>>>(dst, off, nEdges);
    // 3) multi-block exclusive scan -> off, cur
    scan_reduce_kernel<<<nSB, 256, 0, stream>>>(off, blockSums, nNodes);
    scan_sums_kernel<<<1, 256, 0, stream>>>(blockSums, off, nSB, nNodes, nEdges);
    scan_write_kernel<<<nSB, 1024, 0, stream>>>(off, cur, blockSums, nNodes);
    // 4) fill sorted src lists, XCD-partitioned by destination range
    {
        const int blocksPerXcd = 256;   // 2048 blocks total, ~8 waves/CU
        fill_xcd_kernel<<<blocksPerXcd * NXCD, 256, 0, stream>>>(
            src, dst, cur, ssrc, nEdges, nNodes, blocksPerXcd);
    }
    // 5) aggregate: out = x + segment_sum(x[src])
    {
        long long work = (long long)nNodes * 16;
        aggregate_kernel<<<(int)((work + 255) / 256), 256, 0, stream>>>(x, off, ssrc, out, nNodes);
    }
    // 6) MLP in-place
    mlp_kernel<<<(nNodes + 255) / 256, 256, 0, stream>>>(out, W1, b1, W2, b2, out, nNodes);
}